// Round 9
// baseline (833.497 us; speedup 1.0000x reference)
//
#include <hip/hip_runtime.h>
#include <hip/hip_fp16.h>

#define N_NODES 50000
#define N_EDGES 800000
#define IN_C 128
#define HID 32
#define HC 128
#define OUT_C 16
#define NGRAPH 64
#define PNB 125  // nodes per block in pool
#define TPB 4    // targets per block in edge attn

typedef __attribute__((ext_vector_type(8))) _Float16 half8;
typedef __attribute__((ext_vector_type(4))) _Float16 half4v;
typedef __attribute__((ext_vector_type(4))) float floatx4;

// ---------------- CSR build ----------------
__global__ void k_hist(const int* __restrict__ tgt, int* __restrict__ deg) {
  int i = blockIdx.x * blockDim.x + threadIdx.x;
  if (i < N_EDGES) atomicAdd(&deg[tgt[i]], 1);
}

__global__ __launch_bounds__(1024) void k_scan(const int* __restrict__ deg,
                                               int* __restrict__ offs,
                                               int* __restrict__ cursor) {
  __shared__ int wsum[16];
  __shared__ int carry_s;
  int lane = threadIdx.x & 63, wid = threadIdx.x >> 6;
  if (threadIdx.x == 0) { carry_s = 0; offs[0] = 0; }
  __syncthreads();
  for (int base = 0; base < N_NODES; base += 1024) {
    int i = base + threadIdx.x;
    int v = (i < N_NODES) ? deg[i] : 0;
    int x = v;
#pragma unroll
    for (int off = 1; off < 64; off <<= 1) {
      int t = __shfl_up(x, off, 64);
      if (lane >= off) x += t;
    }
    if (lane == 63) wsum[wid] = x;
    __syncthreads();
    if (wid == 0 && lane < 16) {
      int s = wsum[lane];
#pragma unroll
      for (int off = 1; off < 16; off <<= 1) {
        int t = __shfl_up(s, off, 64);
        if (lane >= off) s += t;
      }
      wsum[lane] = s;
    }
    __syncthreads();
    int add = (wid > 0 ? wsum[wid - 1] : 0) + carry_s;
    int incl = x + add;
    if (i < N_NODES) { offs[i + 1] = incl; cursor[i] = incl - v; }
    __syncthreads();
    if (threadIdx.x == 1023) carry_s = incl;
    __syncthreads();
  }
}

// scatter edges into CSR order; also reorder+convert edge_attr to fp16 so the
// edge kernel reads it as a coalesced stream (no eid indirection).
__global__ void k_scatter(const int* __restrict__ src, const int* __restrict__ tgt,
                          const float* __restrict__ ea, int* __restrict__ cursor,
                          int* __restrict__ srcs, _Float16* __restrict__ eas) {
  int i = blockIdx.x * blockDim.x + threadIdx.x;
  if (i < N_EDGES) {
    int pos = atomicAdd(&cursor[tgt[i]], 1);
    srcs[pos] = src[i];
#pragma unroll
    for (int d = 0; d < 32; d += 8) {
      float4 a = *(const float4*)&ea[(size_t)i * HID + d];
      float4 b = *(const float4*)&ea[(size_t)i * HID + d + 4];
      half8 h = {(_Float16)a.x, (_Float16)a.y, (_Float16)a.z, (_Float16)a.w,
                 (_Float16)b.x, (_Float16)b.y, (_Float16)b.z, (_Float16)b.w};
      *(half8*)&eas[(size_t)pos * HID + d] = h;
    }
  }
}

// ---------------- conversions ----------------
__global__ void k_conv_x(const float* __restrict__ x, _Float16* __restrict__ x16) {
  int i = blockIdx.x * 256 + threadIdx.x;
  if (i < N_NODES * HC) x16[i] = (_Float16)x[i];
}

// W^T packed [512 cols][128 k] fp16. One block per output col.
__global__ __launch_bounds__(128) void k_conv_w(
    const float* __restrict__ wq, const float* __restrict__ wk,
    const float* __restrict__ wv, const float* __restrict__ ws,
    _Float16* __restrict__ wt) {
  int g = blockIdx.x;
  int k = threadIdx.x;
  const float* w = (g < 128) ? wq : (g < 256) ? wk : (g < 384) ? wv : ws;
  int c = g & 127;
  wt[g * HC + k] = (_Float16)w[k * HC + c];
}

// ---------------- MFMA node GEMM ----------------
// Grid (782 row-tiles, 4 matrices). Wave owns 16 rows x 128 cols. fp16 in, fp32 acc.
__global__ __launch_bounds__(256) void k_gemm(
    const _Float16* __restrict__ ain,
    const _Float16* __restrict__ wt,
    const float* __restrict__ bq, const float* __restrict__ bk,
    const float* __restrict__ bv, const float* __restrict__ bs,
    __half* __restrict__ qn16, __half* __restrict__ kn16,
    __half* __restrict__ vn16, __half* __restrict__ sk16) {
  int wv = threadIdx.x >> 6, lane = threadIdx.x & 63;
  int quad = lane >> 4, l16 = lane & 15;
  int r0 = blockIdx.x * 64 + wv * 16;
  int cb = blockIdx.y;
  half8 A[4];
  int arow = min(r0 + l16, N_NODES - 1);
#pragma unroll
  for (int kc = 0; kc < 4; ++kc)
    A[kc] = *(const half8*)&ain[(size_t)arow * HC + kc * 32 + quad * 8];
  floatx4 acc[8];
#pragma unroll
  for (int ct = 0; ct < 8; ++ct) acc[ct] = (floatx4){0.f, 0.f, 0.f, 0.f};
#pragma unroll
  for (int ct = 0; ct < 8; ++ct) {
    int col = (cb << 7) + (ct << 4) + l16;
#pragma unroll
    for (int kc = 0; kc < 4; ++kc) {
      half8 B = *(const half8*)&wt[(size_t)col * HC + kc * 32 + quad * 8];
      acc[ct] = __builtin_amdgcn_mfma_f32_16x16x32_f16(A[kc], B, acc[ct], 0, 0, 0);
    }
  }
  const float* bias = (cb == 0) ? bq : (cb == 1) ? bk : (cb == 2) ? bv : bs;
  __half* dst = (cb == 0) ? qn16 : (cb == 1) ? kn16 : (cb == 2) ? vn16 : sk16;
#pragma unroll
  for (int ct = 0; ct < 8; ++ct) {
    int lc = (ct << 4) + l16;
    float b = bias[lc];
#pragma unroll
    for (int reg = 0; reg < 4; ++reg) {
      int row = r0 + quad * 4 + reg;     // C/D: col=lane&15, row=quad*4+reg
      if (row < N_NODES)
        dst[(size_t)row * HC + lc] = __float2half(acc[ct][reg] + b);
    }
  }
}

// ---------------- p = per-head q @ we^T ----------------
__global__ __launch_bounds__(128) void k_pcomp(const __half* __restrict__ qn16,
                                               const float* __restrict__ we,
                                               float* __restrict__ p) {
  int c = threadIdx.x;
  int n0 = blockIdx.x * 16;
  __shared__ float qs[16][HC];
#pragma unroll
  for (int i = 0; i < 16; ++i)
    qs[i][c] = __half2float(qn16[(size_t)(n0 + i) * HC + c]);
  __syncthreads();
  int hb = (c >> 5) << 5, j = c & 31;
  float a[16];
#pragma unroll
  for (int i = 0; i < 16; ++i) a[i] = 0.f;
  for (int d = 0; d < 32; ++d) {
    float wev = we[j * HC + hb + d];
#pragma unroll
    for (int i = 0; i < 16; ++i) a[i] = fmaf(qs[i][hb + d], wev, a[i]);
  }
#pragma unroll
  for (int i = 0; i < 16; ++i) p[(size_t)(n0 + i) * HC + c] = a[i];
}

// ---------------- edge attention ----------------
// 4 waves/block, one target per wave. 4 edges per iteration: 16 lanes/edge,
// lane owns 8 features (half8 loads). Head = 4-lane group -> 2-shfl dot reduce.
// ea is pre-sorted into CSR order (fp16) -> streaming load, no indirection.
// 4 softmax states (one per edge slot) merged by shfl_xor(16/32) at the end.
__global__ __launch_bounds__(256) void k_edge_attn(
    const int* __restrict__ offs, const int* __restrict__ srcs,
    const _Float16* __restrict__ eas, const __half* __restrict__ qn16,
    const __half* __restrict__ kn16, const __half* __restrict__ vn16,
    const __half* __restrict__ sk16, const float* __restrict__ p,
    const float* __restrict__ we,
    float* __restrict__ out, _Float16* __restrict__ o16) {
  int lane = threadIdx.x & 63;
  int wv_ = threadIdx.x >> 6;
  int t = blockIdx.x * TPB + wv_;
  int l16 = lane & 15;
  int eslot = lane >> 4;            // edge slot 0..3
  int f = 8 * l16;                  // feature base 0..120
  int h = l16 >> 2;                 // head 0..3
  int d0 = f & 31;                  // ea dim base (8*(l16&3))
  int e0 = offs[t], e1 = offs[t + 1];
  half8 qh = *(const half8*)&qn16[(size_t)t * HC + f];
  float q[8], pv[8];
  float4 p0 = *(const float4*)&p[(size_t)t * HC + f];
  float4 p1 = *(const float4*)&p[(size_t)t * HC + f + 4];
  pv[0] = p0.x; pv[1] = p0.y; pv[2] = p0.z; pv[3] = p0.w;
  pv[4] = p1.x; pv[5] = p1.y; pv[6] = p1.z; pv[7] = p1.w;
#pragma unroll
  for (int i = 0; i < 8; ++i) q[i] = (float)qh[i];
  const float inv_sqrt = 0.17677669529663687f;
  float m = -1e30f, den = 0.f;
  float acc[8], tac[8];
#pragma unroll
  for (int i = 0; i < 8; ++i) { acc[i] = 0.f; tac[i] = 0.f; }
  for (int base = e0; base < e1; base += 64) {
    int cnt = min(64, e1 - base);
    int li = base + lane;
    int sl = (li < e1) ? srcs[li] : 0;
    for (int jj = 0; jj < cnt; jj += 4) {
      int j = jj + eslot;
      bool val = (j < cnt);
      int jc = min(j, cnt - 1);
      int s = __shfl(sl, jc, 64);
      half8 kh = *(const half8*)&kn16[(size_t)s * HC + f];
      half8 vh = *(const half8*)&vn16[(size_t)s * HC + f];
      half8 eh = *(const half8*)&eas[(size_t)(base + jc) * HID + d0];
      float ev[8];
#pragma unroll
      for (int i = 0; i < 8; ++i) ev[i] = (float)eh[i];
      float part = 0.f;
#pragma unroll
      for (int i = 0; i < 8; ++i)
        part = fmaf(q[i], (float)kh[i], fmaf(pv[i], ev[i], part));
      part += __shfl_xor(part, 1, 64);
      part += __shfl_xor(part, 2, 64);
      float a = part * inv_sqrt;
      float nm = fmaxf(m, a);
      float sc = __expf(m - nm);
      float w = val ? __expf(a - nm) : 0.f;
      m = nm;
      den = fmaf(den, sc, w);
#pragma unroll
      for (int i = 0; i < 8; ++i) {
        acc[i] = fmaf(acc[i], sc, w * (float)vh[i]);
        tac[i] = fmaf(tac[i], sc, w * ev[i]);
      }
    }
  }
  // merge the 4 edge-slot states (xor 16, then 32)
#pragma unroll
  for (int d = 16; d <= 32; d <<= 1) {
    float m_o = __shfl_xor(m, d, 64);
    float M = fmaxf(m, m_o);
    float s_s = __expf(m - M), s_o = __expf(m_o - M);
    float den_o = __shfl_xor(den, d, 64);
    den = fmaf(den, s_s, den_o * s_o);
#pragma unroll
    for (int i = 0; i < 8; ++i) {
      acc[i] = fmaf(acc[i], s_s, __shfl_xor(acc[i], d, 64) * s_o);
      tac[i] = fmaf(tac[i], s_s, __shfl_xor(tac[i], d, 64) * s_o);
    }
    m = M;
  }
  // fixup: (sum_e a_e * ea_e) @ we, per head. Row pad 36 -> 16B-aligned, no conflicts.
  __shared__ float tl[TPB][4 * 36];
  if (eslot == 0) {
    *(float4*)&tl[wv_][h * 36 + d0] = (float4){tac[0], tac[1], tac[2], tac[3]};
    *(float4*)&tl[wv_][h * 36 + d0 + 4] = (float4){tac[4], tac[5], tac[6], tac[7]};
  }
  // wave-private LDS region: compiler inserts lgkmcnt waits
  float fx[8];
#pragma unroll
  for (int i = 0; i < 8; ++i) fx[i] = 0.f;
  for (int j = 0; j < 32; ++j) {
    float tv = tl[wv_][h * 36 + j];
    float4 w0 = *(const float4*)&we[j * HC + f];
    float4 w1 = *(const float4*)&we[j * HC + f + 4];
    fx[0] = fmaf(tv, w0.x, fx[0]); fx[1] = fmaf(tv, w0.y, fx[1]);
    fx[2] = fmaf(tv, w0.z, fx[2]); fx[3] = fmaf(tv, w0.w, fx[3]);
    fx[4] = fmaf(tv, w1.x, fx[4]); fx[5] = fmaf(tv, w1.y, fx[5]);
    fx[6] = fmaf(tv, w1.z, fx[6]); fx[7] = fmaf(tv, w1.w, fx[7]);
  }
  if (eslot == 0) {
    half8 skh = *(const half8*)&sk16[(size_t)t * HC + f];
    float rd = (e1 > e0) ? (1.0f / den) : 0.f;
    float o[8];
#pragma unroll
    for (int i = 0; i < 8; ++i) {
      float v = (acc[i] + fx[i]) * rd + (float)skh[i];
      o[i] = v > 0.f ? v : __expf(v) - 1.f;   // ELU
    }
    *(float4*)&out[(size_t)t * HC + f] = (float4){o[0], o[1], o[2], o[3]};
    *(float4*)&out[(size_t)t * HC + f + 4] = (float4){o[4], o[5], o[6], o[7]};
    half8 v16 = {(_Float16)o[0], (_Float16)o[1], (_Float16)o[2], (_Float16)o[3],
                 (_Float16)o[4], (_Float16)o[5], (_Float16)o[6], (_Float16)o[7]};
    *(half8*)&o16[(size_t)t * HC + f] = v16;
  }
}

// ---------------- global mean pool ----------------
__global__ __launch_bounds__(128) void k_pool_sum(const float* __restrict__ h,
                                                  const int* __restrict__ batch,
                                                  float* __restrict__ psum) {
  int c = threadIdx.x;
  int n0 = blockIdx.x * PNB;
  int n1 = n0 + PNB;
  float acc = 0.f;
  int curb = batch[n0];
  for (int n = n0; n < n1; ++n) {
    int b = batch[n];
    if (b != curb) {
      atomicAdd(&psum[curb * HC + c], acc);
      acc = 0.f;
      curb = b;
    }
    acc += h[n * HC + c];
  }
  atomicAdd(&psum[curb * HC + c], acc);
}

// ---------------- classifier + log_softmax ----------------
__global__ __launch_bounds__(1024) void k_classify(const float* __restrict__ psum,
                                                   const int* __restrict__ batch,
                                                   const float* __restrict__ wlin,
                                                   const float* __restrict__ blin,
                                                   float* __restrict__ out) {
  int tid = threadIdx.x;
  int b = tid >> 4, o = tid & 15;
  int lo = 0, hi = N_NODES;
  while (lo < hi) { int mid = (lo + hi) >> 1; if (batch[mid] < b) lo = mid + 1; else hi = mid; }
  int start = lo;
  lo = 0; hi = N_NODES;
  while (lo < hi) { int mid = (lo + hi) >> 1; if (batch[mid] <= b) lo = mid + 1; else hi = mid; }
  float cnt = fmaxf((float)(lo - start), 1.0f);
  float dot = 0.f;
  for (int d = 0; d < HC; ++d) dot = fmaf(psum[b * HC + d], wlin[d * OUT_C + o], dot);
  float acc = dot / cnt + blin[o];
  float mx = acc;
#pragma unroll
  for (int off = 8; off > 0; off >>= 1) mx = fmaxf(mx, __shfl_xor(mx, off, 64));
  float ex = __expf(acc - mx);
  float sum = ex;
#pragma unroll
  for (int off = 8; off > 0; off >>= 1) sum += __shfl_xor(sum, off, 64);
  out[tid] = acc - mx - logf(sum);
}

extern "C" void kernel_launch(void* const* d_in, const int* in_sizes, int n_in,
                              void* d_out, int out_size, void* d_ws, size_t ws_size,
                              hipStream_t stream) {
  const float* x = (const float*)d_in[0];
  const int* ei = (const int*)d_in[1];
  const float* ea = (const float*)d_in[2];
  const int* batch = (const int*)d_in[3];
  const float* wq1 = (const float*)d_in[4];  const float* bq1 = (const float*)d_in[5];
  const float* wk1 = (const float*)d_in[6];  const float* bk1 = (const float*)d_in[7];
  const float* wv1 = (const float*)d_in[8];  const float* bv1 = (const float*)d_in[9];
  const float* we1 = (const float*)d_in[10];
  const float* ws1 = (const float*)d_in[11]; const float* bs1 = (const float*)d_in[12];
  const float* wq2 = (const float*)d_in[13]; const float* bq2 = (const float*)d_in[14];
  const float* wk2 = (const float*)d_in[15]; const float* bk2 = (const float*)d_in[16];
  const float* wv2 = (const float*)d_in[17]; const float* bv2 = (const float*)d_in[18];
  const float* we2 = (const float*)d_in[19];
  const float* ws2 = (const float*)d_in[20]; const float* bs2 = (const float*)d_in[21];
  const float* wlin = (const float*)d_in[22]; const float* blin = (const float*)d_in[23];

  const int* srcI = ei;
  const int* tgtI = ei + N_EDGES;

  char* wsb = (char*)d_ws;
  size_t off = 0;
  auto alloc = [&](size_t bytes) -> void* {
    void* ptr = wsb + off;
    off += (bytes + 255) & ~(size_t)255;
    return ptr;
  };
  __half* qn16 = (__half*)alloc((size_t)N_NODES * HC * 2);
  __half* kn16 = (__half*)alloc((size_t)N_NODES * HC * 2);
  __half* vn16 = (__half*)alloc((size_t)N_NODES * HC * 2);
  __half* sk16 = (__half*)alloc((size_t)N_NODES * HC * 2);
  float* p  = (float*)alloc((size_t)N_NODES * HC * 4);
  float* h  = (float*)alloc((size_t)N_NODES * HC * 4);
  _Float16* in16 = (_Float16*)alloc((size_t)N_NODES * HC * 2);  // x16, then h16
  _Float16* wt1 = (_Float16*)alloc((size_t)512 * HC * 2);
  _Float16* wt2 = (_Float16*)alloc((size_t)512 * HC * 2);
  _Float16* eas = (_Float16*)alloc((size_t)N_EDGES * HID * 2);  // CSR-ordered fp16 edge attr
  float* psum = (float*)alloc((size_t)NGRAPH * HC * 4);
  int* deg    = (int*)alloc((size_t)N_NODES * 4);
  int* offs   = (int*)alloc((size_t)(N_NODES + 1) * 4);
  int* cursor = (int*)alloc((size_t)N_NODES * 4);
  int* srcs   = (int*)alloc((size_t)N_EDGES * 4);

  // CSR build (+ ea reorder/convert)
  hipMemsetAsync(deg, 0, (size_t)N_NODES * 4, stream);
  k_hist<<<(N_EDGES + 255) / 256, 256, 0, stream>>>(tgtI, deg);
  k_scan<<<1, 1024, 0, stream>>>(deg, offs, cursor);
  k_scatter<<<(N_EDGES + 255) / 256, 256, 0, stream>>>(srcI, tgtI, ea, cursor, srcs, eas);

  // Conversions
  k_conv_x<<<(N_NODES * HC + 255) / 256, 256, 0, stream>>>(x, in16);
  k_conv_w<<<512, 128, 0, stream>>>(wq1, wk1, wv1, ws1, wt1);
  k_conv_w<<<512, 128, 0, stream>>>(wq2, wk2, wv2, ws2, wt2);

  dim3 gemm_grid((N_NODES + 63) / 64, 4);
  // Layer 1
  k_gemm<<<gemm_grid, 256, 0, stream>>>(in16, wt1, bq1, bk1, bv1, bs1,
                                        qn16, kn16, vn16, sk16);
  k_pcomp<<<N_NODES / 16, 128, 0, stream>>>(qn16, we1, p);
  k_edge_attn<<<N_NODES / TPB, 64 * TPB, 0, stream>>>(offs, srcs, eas, qn16,
                                                      kn16, vn16, sk16, p, we1, h, in16);
  // Layer 2
  k_gemm<<<gemm_grid, 256, 0, stream>>>(in16, wt2, bq2, bk2, bv2, bs2,
                                        qn16, kn16, vn16, sk16);
  k_pcomp<<<N_NODES / 16, 128, 0, stream>>>(qn16, we2, p);
  k_edge_attn<<<N_NODES / TPB, 64 * TPB, 0, stream>>>(offs, srcs, eas, qn16,
                                                      kn16, vn16, sk16, p, we2, h, in16);

  // Pool + classify
  hipMemsetAsync(psum, 0, (size_t)NGRAPH * HC * 4, stream);
  k_pool_sum<<<N_NODES / PNB, 128, 0, stream>>>(h, batch, psum);
  k_classify<<<1, 1024, 0, stream>>>(psum, batch, wlin, blin, (float*)d_out);
}